// Round 11
// baseline (263.510 us; speedup 1.0000x reference)
//
#include <hip/hip_runtime.h>
#include <hip/hip_bf16.h>
#include <math.h>

// Problem dims (fixed by setup_inputs)
#define Bz 4
#define Nn 1024
#define Cc 768
#define Hh 12
#define Dd 64
#define BN 4096          // B*N
#define NC 16            // chunks per sequence
#define BH 48            // B*H
#define OUT_ELEMS 3145728  // BN*C

// ---------------- workspace layout ----------------
// float offsets:
#define WS_U       0u          // f32 [768 tiles][4096]
#define WS_PLIG    3145728u    // f32 [BN][128] (72 used: prune60|idgate12)
#define WS_GL      3670016u    // f32 [BN][128] (12 used)
#define WS_ENT     4194304u    // [1024]
#define WS_FIRST   4195328u    // [3][768]
#define WS_FIRLT   4197632u    // [7][768]
#define WS_CBIAS   4203008u    // [3968]
#define WS_GBIAS   4206976u    // [128]
#define WS_SH      4207104u    // shorts region starts here (float offset)
// short offsets within the bf16 region:
#define SH_XB      0u          // [BN][768]
#define SH_QKVB    3145728u    // [BN][2304]
#define SH_IDOUT   12582912u   // [BN][768]
#define SH_HDNB    15728640u   // [BN][768]
#define SH_CTXB    18874368u   // [BN][768]
#define SH_DELTA   22020096u   // [BN][768]
#define SH_QS      25165824u   // [768 tiles][4096]
#define SH_KNT     28311552u
#define SH_W       31457280u
#define SH_AT      34603008u
#define SH_WCAT2T  37748736u   // [3968][768]: wqkvT|w_idT|w_g1T|wcombT(72)+pad
#define SH_G2T     40796160u   // [128][768]
#define SH_WPROJT  40894464u   // [768][768]

typedef __attribute__((ext_vector_type(8))) short bf16x8;
typedef __attribute__((ext_vector_type(4))) float f32x4;

__device__ __forceinline__ float sigmoidf_(float x) { return 1.f / (1.f + __expf(-x)); }
__device__ __forceinline__ float geluf_(float x) {
    float t = tanhf(0.7978845608028654f * (x + 0.044715f * x * x * x));
    return 0.5f * x * (1.f + t);
}
__device__ __forceinline__ short bf16c(float f) {
    union { float f; unsigned u; } a; a.f = f;
    unsigned r = a.u + 0x7fffu + ((a.u >> 16) & 1u);
    return (short)(r >> 16);
}
__device__ __forceinline__ float b2f(short s) {
    union { float f; unsigned u; } a;
    a.u = ((unsigned)(unsigned short)s) << 16;
    return a.f;
}
__device__ __forceinline__ void gload16(const void* g, void* l) {
    __builtin_amdgcn_global_load_lds(
        (const __attribute__((address_space(1))) unsigned*)g,
        (__attribute__((address_space(3))) unsigned*)l, 16, 0, 0);
}
// MFMA fragment read from a 64x64 bf16 LDS array with per-row XOR granule swizzle.
__device__ __forceinline__ bf16x8 frag_(const short* arr, int row, int kc, int quad) {
    return *(const bf16x8*)&arr[row * 64 + (((kc * 4 + quad) ^ (row & 7)) << 3)];
}

// -------- weight transpose + bf16 convert (z=0..3) + prep (z=4) + x (z=5) ----
__global__ __launch_bounds__(256) void convert_w_kernel(const float* __restrict__ w_qkv,
        const float* __restrict__ w_id, const float* __restrict__ w_g1,
        const float* __restrict__ w_proj, short* __restrict__ wcat2T,
        short* __restrict__ wprojT,
        const float* __restrict__ wp, const float* __restrict__ wig,
        const float* __restrict__ bp, const float* __restrict__ big,
        const float* __restrict__ bg1, const float* __restrict__ bg2,
        const float* __restrict__ wg2, const float* __restrict__ firs,
        const float* __restrict__ firl, short* __restrict__ g2T,
        float* __restrict__ cbias, float* __restrict__ gbias,
        float* __restrict__ firsT, float* __restrict__ firlT,
        const float* __restrict__ x, short* __restrict__ xb) {
    __shared__ float t[64][65];
    const int z = blockIdx.z;
    const int tid = threadIdx.x;
    if (z == 5) {
        // x f32 -> bf16 (grid-stride over 786432 float4 groups)
        for (int i = (blockIdx.y * 12 + blockIdx.x) * 256 + tid; i < 786432;
             i += 110592) {
            float4 v = *(const float4*)&x[(size_t)i * 4];
            short4 o;
            o.x = bf16c(v.x); o.y = bf16c(v.y); o.z = bf16c(v.z); o.w = bf16c(v.w);
            *(short4*)&xb[(size_t)i * 4] = o;
        }
        return;
    }
    if (z == 4) {
        int i = (blockIdx.y * 12 + blockIdx.x) * 256 + tid;
        if (i < 98304) {
            int r = i / 768, k = i % 768;
            float wv = 0.f;
            if (r < 60) wv = wp[k * 60 + r];
            else if (r < 72) wv = wig[k * 12 + (r - 60)];
            wcat2T[(size_t)(3840 + r) * 768 + k] = (r < 72) ? bf16c(wv) : (short)0;
            g2T[(size_t)r * 768 + k] = (r < 12) ? bf16c(wg2[k * 12 + r]) : (short)0;
        }
        if (i < 3968) {
            float bv = 0.f;
            if (i >= 3072 && i < 3840) bv = bg1[i - 3072];
            else if (i >= 3840 && i < 3900) bv = bp[i - 3840];
            else if (i >= 3900 && i < 3912) bv = big[i - 3900];
            cbias[i] = bv;
        }
        if (i < 128) gbias[i] = (i < 12) ? bg2[i] : 0.f;
        if (i < 2304) { int tt = i / 768, e = i % 768; firsT[tt * 768 + e] = firs[e * 3 + tt]; }
        if (i < 5376) { int tt = i / 768, e = i % 768; firlT[tt * 768 + e] = firl[e * 7 + tt]; }
        return;
    }
    const float* src; short* dst; int Nw;
    if (z == 0)      { src = w_qkv;  dst = wcat2T;               Nw = 2304; }
    else if (z == 1) { src = w_id;   dst = wcat2T + 2304 * 768;  Nw = 768; }
    else if (z == 2) { src = w_g1;   dst = wcat2T + 3072 * 768;  Nw = 768; }
    else             { src = w_proj; dst = wprojT;               Nw = 768; }
    const int n0 = blockIdx.y * 64;
    if (n0 >= Nw) return;
    const int k0 = blockIdx.x * 64;
    for (int e = tid; e < 1024; e += 256) {
        int r = e >> 4, c4 = (e & 15) * 4;
        float4 v = *(const float4*)&src[(size_t)(k0 + r) * Nw + n0 + c4];
        t[c4 + 0][r] = v.x; t[c4 + 1][r] = v.y;
        t[c4 + 2][r] = v.z; t[c4 + 3][r] = v.w;
    }
    __syncthreads();
    for (int e = tid; e < 1024; e += 256) {
        int r = e >> 4, c4 = (e & 15) * 4;
        short4 o;
        o.x = bf16c(t[r][c4 + 0]); o.y = bf16c(t[r][c4 + 1]);
        o.z = bf16c(t[r][c4 + 2]); o.w = bf16c(t[r][c4 + 3]);
        *(short4*)&dst[(size_t)(n0 + r) * 768 + k0 + c4] = o;
    }
}

// ---------------- shared MFMA K-loop core (128x128 tile, BK=64) --------------
// XCD-aware tile swizzle (requires gridDim.y == 32, total blocks % 8 == 0):
// dispatch-linear L -> xcd = L&7 (HW round-robin), j = L>>3; XCD x owns compact
// patch rows 4x..4x+3 (A strips L2-resident) x all cols (B streamed per XCD).
// Staging via global_load_lds (direct-to-LDS DMA). NOTE (R9 post-mortem):
// register-staged prefetch spilled to scratch (~290MB HBM writes) and
// regressed 257->373us -- do not hand-pipeline this structure.
#define GEMM_CORE(APTR, BPTR, KDIM)                                            \
    __shared__ short As[128 * 64];                                             \
    __shared__ short Bs[128 * 64];                                             \
    const int tid = threadIdx.x;                                               \
    const int lane = tid & 63, w = tid >> 6;                                   \
    const int quad = lane >> 4, l15 = lane & 15;                               \
    const int L_ = blockIdx.y * gridDim.x + blockIdx.x;                        \
    const int xcd_ = L_ & 7, j_ = L_ >> 3;                                     \
    const int row0 = (xcd_ * 4 + (j_ & 3)) * 128, col0 = (j_ >> 2) * 128;      \
    const int wm = (w >> 1) * 64, wn = (w & 1) * 64;                           \
    int srow[4]; int scol[4];                                                  \
    _Pragma("unroll") for (int i = 0; i < 4; ++i) {                            \
        int G = (w * 4 + i) * 64 + lane;                                       \
        int row = G >> 3, g = G & 7;                                           \
        srow[i] = row;                                                         \
        scol[i] = (g ^ (row & 7)) * 8;                                         \
    }                                                                          \
    int aoff[4][2], boff[4][2];                                                \
    _Pragma("unroll") for (int mi = 0; mi < 4; ++mi)                           \
        _Pragma("unroll") for (int kk = 0; kk < 2; ++kk) {                     \
            int ra = wm + mi * 16 + l15;                                       \
            aoff[mi][kk] = ra * 128 + (((kk * 4 + quad) ^ (ra & 7)) * 16);     \
            int rb = wn + mi * 16 + l15;                                       \
            boff[mi][kk] = rb * 128 + (((kk * 4 + quad) ^ (rb & 7)) * 16);     \
        }                                                                      \
    f32x4 acc[4][4];                                                           \
    _Pragma("unroll") for (int mi = 0; mi < 4; ++mi)                           \
        _Pragma("unroll") for (int ni = 0; ni < 4; ++ni) acc[mi][ni] = (f32x4)0.f; \
    for (int k0 = 0; k0 < (KDIM); k0 += 64) {                                  \
        _Pragma("unroll") for (int i = 0; i < 4; ++i) {                        \
            gload16(&(APTR)[(size_t)(row0 + srow[i]) * (KDIM) + k0 + scol[i]], \
                    &As[(w * 4 + i) * 512]);                                   \
            gload16(&(BPTR)[(size_t)(col0 + srow[i]) * (KDIM) + k0 + scol[i]], \
                    &Bs[(w * 4 + i) * 512]);                                   \
        }                                                                      \
        __syncthreads();                                                       \
        _Pragma("unroll") for (int kk = 0; kk < 2; ++kk) {                     \
            bf16x8 af[4], bfr[4];                                              \
            _Pragma("unroll") for (int mi = 0; mi < 4; ++mi)                   \
                af[mi] = *(const bf16x8*)((const char*)As + aoff[mi][kk]);     \
            _Pragma("unroll") for (int ni = 0; ni < 4; ++ni)                   \
                bfr[ni] = *(const bf16x8*)((const char*)Bs + boff[ni][kk]);    \
            _Pragma("unroll") for (int mi = 0; mi < 4; ++mi)                   \
                _Pragma("unroll") for (int ni = 0; ni < 4; ++ni)               \
                    acc[mi][ni] = __builtin_amdgcn_mfma_f32_16x16x32_bf16(     \
                        af[mi], bfr[ni], acc[mi][ni], 0, 0, 0);                \
        }                                                                      \
        __syncthreads();                                                       \
    }

// ---------------- fused main projection: x @ [wqkv|w_id|w_g1|wcomb] ----------
__global__ __launch_bounds__(256) void gemm_main(const short* __restrict__ A,
        const short* __restrict__ BT, const float* __restrict__ bias,
        short* __restrict__ qkvb, short* __restrict__ idoutb,
        short* __restrict__ hdnb, float* __restrict__ plig) {
    GEMM_CORE(A, BT, 768)
#pragma unroll
    for (int ni = 0; ni < 4; ++ni) {
        int col = col0 + wn + ni * 16 + l15;
        float bv = bias[col];
#pragma unroll
        for (int mi = 0; mi < 4; ++mi) {
#pragma unroll
            for (int r = 0; r < 4; ++r) {
                int row = row0 + wm + mi * 16 + quad * 4 + r;
                float v = acc[mi][ni][r] + bv;
                if (col < 2304) {
                    qkvb[(size_t)row * 2304 + col] = bf16c(v);
                } else if (col < 3072) {
                    idoutb[(size_t)row * 768 + (col - 2304)] = bf16c(v);
                } else if (col < 3840) {
                    hdnb[(size_t)row * 768 + (col - 3072)] = bf16c(geluf_(v));
                } else {
                    plig[(size_t)row * 128 + (col - 3840)] = v;
                }
            }
        }
    }
}

// -------- generic bf16 MFMA GEMM (+ optional fused entropy finalize) ---------
__global__ __launch_bounds__(256) void gemm_mfma(const short* __restrict__ A,
        const short* __restrict__ BT, const float* __restrict__ bias,
        float* __restrict__ C, int M, int N, int K,
        const float* __restrict__ slots, float* __restrict__ entout) {
    __shared__ float red[256];
    GEMM_CORE(A, BT, K)
#pragma unroll
    for (int ni = 0; ni < 4; ++ni) {
        int col = col0 + wn + ni * 16 + l15;
        float bv = bias ? bias[col] : 0.f;
#pragma unroll
        for (int mi = 0; mi < 4; ++mi) {
#pragma unroll
            for (int r = 0; r < 4; ++r) {
                int row = row0 + wm + mi * 16 + quad * 4 + r;
                C[(size_t)row * N + col] = acc[mi][ni][r] + bv;
            }
        }
    }
    if (slots && L_ == 0) {
        float s = 0.f;
        for (int i = tid; i < 1024; i += 256) s += slots[i];
        red[tid] = s;
        __syncthreads();
        for (int off = 128; off > 0; off >>= 1) {
            if (tid < off) red[tid] += red[tid + off];
            __syncthreads();
        }
        if (tid == 0) entout[0] = -red[0] * (1.f / 49152.f);
    }
}

// ------- delta-rule preprocessing (768 blocks) + gate GEMM (32 blocks) -------
// Blocks 0..767: per 64x64 chunk tile Qsb16/Kntb16/Wb16/Atb16 bf16, U f32.
// Blocks 768..799: gl = hdnb @ g2T^T + gbias (N=128) -- merged so its 32
// blocks don't occupy a solo dispatch leaving 87% of CUs idle.
__global__ __launch_bounds__(256) void pre_gl_kernel(const short* __restrict__ qkvb,
        short* __restrict__ Qsb16, short* __restrict__ Kntb16, float* __restrict__ U,
        short* __restrict__ Wb16, short* __restrict__ Atb16,
        const short* __restrict__ hdnb, const short* __restrict__ g2T,
        const float* __restrict__ gbias, float* __restrict__ gl) {
    __shared__ __align__(16) char smem[50176];
    const int blk = blockIdx.x;
    const int tid = threadIdx.x;
    const int lane = tid & 63, w = tid >> 6;
    const int quad = lane >> 4, l15 = lane & 15;

    if (blk >= 768) {
        // ---- gate GEMM: 128x128 tile, row0 = idx*128, col0 = 0, K = 768 ----
        short* As = (short*)smem;
        short* Bs = (short*)(smem + 16384);
        const int row0 = (blk - 768) * 128;
        const int wm = (w >> 1) * 64, wn = (w & 1) * 64;
        int srow[4], scol[4];
#pragma unroll
        for (int i = 0; i < 4; ++i) {
            int G = (w * 4 + i) * 64 + lane;
            int row = G >> 3, g = G & 7;
            srow[i] = row;
            scol[i] = (g ^ (row & 7)) * 8;
        }
        int aoff[4][2], boff[4][2];
#pragma unroll
        for (int mi = 0; mi < 4; ++mi)
#pragma unroll
            for (int kk = 0; kk < 2; ++kk) {
                int ra = wm + mi * 16 + l15;
                aoff[mi][kk] = ra * 128 + (((kk * 4 + quad) ^ (ra & 7)) * 16);
                int rb = wn + mi * 16 + l15;
                boff[mi][kk] = rb * 128 + (((kk * 4 + quad) ^ (rb & 7)) * 16);
            }
        f32x4 acc[4][4];
#pragma unroll
        for (int mi = 0; mi < 4; ++mi)
#pragma unroll
            for (int ni = 0; ni < 4; ++ni) acc[mi][ni] = (f32x4)0.f;
        for (int k0 = 0; k0 < 768; k0 += 64) {
#pragma unroll
            for (int i = 0; i < 4; ++i) {
                gload16(&hdnb[(size_t)(row0 + srow[i]) * 768 + k0 + scol[i]],
                        &As[(w * 4 + i) * 512]);
                gload16(&g2T[(size_t)srow[i] * 768 + k0 + scol[i]],
                        &Bs[(w * 4 + i) * 512]);
            }
            __syncthreads();
#pragma unroll
            for (int kk = 0; kk < 2; ++kk) {
                bf16x8 af[4], bfr[4];
#pragma unroll
                for (int mi = 0; mi < 4; ++mi)
                    af[mi] = *(const bf16x8*)((const char*)As + aoff[mi][kk]);
#pragma unroll
                for (int ni = 0; ni < 4; ++ni)
                    bfr[ni] = *(const bf16x8*)((const char*)Bs + boff[ni][kk]);
#pragma unroll
                for (int mi = 0; mi < 4; ++mi)
#pragma unroll
                    for (int ni = 0; ni < 4; ++ni)
                        acc[mi][ni] = __builtin_amdgcn_mfma_f32_16x16x32_bf16(
                            af[mi], bfr[ni], acc[mi][ni], 0, 0, 0);
            }
            __syncthreads();
        }
#pragma unroll
        for (int ni = 0; ni < 4; ++ni) {
            int col = wn + ni * 16 + l15;
            float bv = gbias[col];
#pragma unroll
            for (int mi = 0; mi < 4; ++mi)
#pragma unroll
                for (int r = 0; r < 4; ++r) {
                    int row = row0 + wm + mi * 16 + quad * 4 + r;
                    gl[(size_t)row * 128 + col] = acc[mi][ni][r] + bv;
                }
        }
        return;
    }

    // ---------------- pre body (blocks 0..767) ----------------
    float (*ts)[68] = (float (*)[68])smem;               // 17408 B
    short* kn  = (short*)(smem + 17408);                 // 8192 B
    short* knt = (short*)(smem + 25600);                 // 8192 B
    short* qsb = (short*)(smem + 33792);                 // 8192 B
    short* vtb = (short*)(smem + 41984);                 // 8192 B
    float (*zbuf)[68] = (float (*)[68])(smem + 17408);   // overlays kn (dead after B)
    short* tb  = (short*)(smem + 33792);                 // overlays qsb (dead after B)
    const int c = blk & 15, bh = blk >> 4;
    const int b = bh / Hh, h = bh % Hh;
    const int r = tid >> 2, d0 = (tid & 3) * 16;
    const size_t rowb = ((size_t)(b * Nn + c * 64)) * 2304 + h * 64;
    const size_t base2 = (size_t)blk * 4096;

    // ---- Phase A: bf16 loads; k-norm; fill LDS; Qsb16 straight to global ----
    {
        const short* qp = &qkvb[rowb + (size_t)r * 2304 + d0];
        bf16x8 qb0 = *(const bf16x8*)&qp[0],    qb1 = *(const bf16x8*)&qp[8];
        bf16x8 kb0 = *(const bf16x8*)&qp[768],  kb1 = *(const bf16x8*)&qp[776];
        bf16x8 vb0 = *(const bf16x8*)&qp[1536], vb1 = *(const bf16x8*)&qp[1544];

        float kf[16];
#pragma unroll
        for (int t = 0; t < 8; ++t) { kf[t] = b2f(kb0[t]); kf[8 + t] = b2f(kb1[t]); }
        float ss = 0.f;
#pragma unroll
        for (int t = 0; t < 16; ++t) ss += kf[t] * kf[t];
        ss += __shfl_xor(ss, 1);
        ss += __shfl_xor(ss, 2);
        float invn = 1.f / (sqrtf(ss) + 1e-6f);
        {
            bf16x8 g0, g1;
#pragma unroll
            for (int t = 0; t < 8; ++t) {
                g0[t] = bf16c(kf[t] * invn); g1[t] = bf16c(kf[8 + t] * invn);
            }
            int gb = d0 >> 3;
            *(bf16x8*)&kn[r * 64 + (((gb + 0) ^ (r & 7)) << 3)] = g0;
            *(bf16x8*)&kn[r * 64 + (((gb + 1) ^ (r & 7)) << 3)] = g1;
#pragma unroll
            for (int t = 0; t < 8; ++t) {
                int d = d0 + t;
                knt[d * 64 + (((r >> 3) ^ (d & 7)) << 3) + (r & 7)] = g0[t];
                int d2 = d0 + 8 + t;
                knt[d2 * 64 + (((r >> 3) ^ (d2 & 7)) << 3) + (r & 7)] = g1[t];
            }
        }
        {
            bf16x8 g0, g1;
#pragma unroll
            for (int t = 0; t < 8; ++t) {
                g0[t] = bf16c(b2f(qb0[t]) * 0.125f);
                g1[t] = bf16c(b2f(qb1[t]) * 0.125f);
            }
            int gb = d0 >> 3;
            *(bf16x8*)&qsb[r * 64 + (((gb + 0) ^ (r & 7)) << 3)] = g0;
            *(bf16x8*)&qsb[r * 64 + (((gb + 1) ^ (r & 7)) << 3)] = g1;
            *(bf16x8*)&Qsb16[base2 + r * 64 + d0] = g0;
            *(bf16x8*)&Qsb16[base2 + r * 64 + d0 + 8] = g1;
        }
#pragma unroll
        for (int t = 0; t < 8; ++t) {
            int d = d0 + t;
            vtb[d * 64 + (((r >> 3) ^ (d & 7)) << 3) + (r & 7)] = vb0[t];
            int d2 = d0 + 8 + t;
            vtb[d2 * 64 + (((r >> 3) ^ (d2 & 7)) << 3) + (r & 7)] = vb1[t];
        }
    }
    __syncthreads();

    // ---- Phase B: A_full = Kn Kn^T -> ts (tril,-1); accT = Qs Kn^T in regs ---
    f32x4 accT[4];
    {
        const int ar = w * 16 + l15;
        bf16x8 aK0 = frag_(kn, ar, 0, quad), aK1 = frag_(kn, ar, 1, quad);
        bf16x8 aQ0 = frag_(qsb, ar, 0, quad), aQ1 = frag_(qsb, ar, 1, quad);
        f32x4 accA[4];
#pragma unroll
        for (int ni = 0; ni < 4; ++ni) {
            int br = ni * 16 + l15;
            bf16x8 b0 = frag_(kn, br, 0, quad), b1 = frag_(kn, br, 1, quad);
            accA[ni] = __builtin_amdgcn_mfma_f32_16x16x32_bf16(aK0, b0, (f32x4)0.f, 0, 0, 0);
            accA[ni] = __builtin_amdgcn_mfma_f32_16x16x32_bf16(aK1, b1, accA[ni], 0, 0, 0);
            accT[ni] = __builtin_amdgcn_mfma_f32_16x16x32_bf16(aQ0, b0, (f32x4)0.f, 0, 0, 0);
            accT[ni] = __builtin_amdgcn_mfma_f32_16x16x32_bf16(aQ1, b1, accT[ni], 0, 0, 0);
        }
#pragma unroll
        for (int ni = 0; ni < 4; ++ni)
#pragma unroll
            for (int reg = 0; reg < 4; ++reg) {
                int row = w * 16 + quad * 4 + reg;
                int col = ni * 16 + l15;
                ts[row][col] = (col < row) ? accA[ni][reg] : 0.f;
            }
    }
    __syncthreads();

    // ---- Phase C1: 4 diagonal 16x16 unit-lower inversions, one per wave ------
    {
        const int R0 = w * 16;
        const int j = lane & 15, s = lane >> 4;
#pragma unroll 1
        for (int i = 0; i < 16; ++i) {
            float p = 0.f;
            for (int m = s; m < i; m += 4)
                p += ts[R0 + i][R0 + m] * ts[R0 + m][R0 + j];
            p += __shfl_xor(p, 16);
            p += __shfl_xor(p, 32);
            if (s == 0) ts[R0 + i][R0 + j] = ((j == i) ? 1.f : 0.f) - p;
        }
    }
    __syncthreads();
    // ---- Phase C2: off-diagonal block rows I=1..3 ----
#pragma unroll 1
    for (int I = 1; I < 4; ++I) {
        const int ncol = I * 16;
        for (int e = tid; e < 16 * ncol; e += 256) {
            int i = e / ncol, jj = e % ncol;
            float s = 0.f;
            for (int m = jj; m < ncol; ++m) s += ts[ncol + i][m] * ts[m][jj];
            zbuf[i][jj] = s;
        }
        __syncthreads();
        for (int e = tid; e < 16 * ncol; e += 256) {
            int i = e / ncol, jj = e % ncol;
            float s = 0.f;
            for (int ml = 0; ml <= i; ++ml) s += ts[ncol + i][ncol + ml] * zbuf[ml][jj];
            ts[ncol + i][jj] = -s;
        }
        __syncthreads();
    }
    // ---- convert T -> bf16 tb (qsb overlay) ----
    for (int e = tid; e < 512; e += 256) {
        int row = e >> 3, g = e & 7;
        bf16x8 o;
#pragma unroll
        for (int t = 0; t < 8; ++t) o[t] = bf16c(ts[row][g * 8 + t]);
        *(bf16x8*)&tb[row * 64 + ((g ^ (row & 7)) << 3)] = o;
    }
    __syncthreads();

    // ---- Phase D: W = T@Kn, U = T@V ----
    f32x4 accW[4], accU[4];
    {
        const int ar = w * 16 + l15;
        bf16x8 aT0 = frag_(tb, ar, 0, quad), aT1 = frag_(tb, ar, 1, quad);
#pragma unroll
        for (int ni = 0; ni < 4; ++ni) {
            int br = ni * 16 + l15;
            bf16x8 b0 = frag_(knt, br, 0, quad), b1 = frag_(knt, br, 1, quad);
            bf16x8 c0 = frag_(vtb, br, 0, quad), c1 = frag_(vtb, br, 1, quad);
            accW[ni] = __builtin_amdgcn_mfma_f32_16x16x32_bf16(aT0, b0, (f32x4)0.f, 0, 0, 0);
            accW[ni] = __builtin_amdgcn_mfma_f32_16x16x32_bf16(aT1, b1, accW[ni], 0, 0, 0);
            accU[ni] = __builtin_amdgcn_mfma_f32_16x16x32_bf16(aT0, c0, (f32x4)0.f, 0, 0, 0);
            accU[ni] = __builtin_amdgcn_mfma_f32_16x16x32_bf16(aT1, c1, accU[ni], 0, 0, 0);
        }
    }
    // ---- Tail: all remaining global stores ----
#pragma unroll
    for (int ni = 0; ni < 4; ++ni)
#pragma unroll
        for (int reg = 0; reg < 4; ++reg) {
            int row = w * 16 + quad * 4 + reg;
            int col = ni * 16 + l15;
            Wb16[base2 + (size_t)row * 64 + col] = bf16c(accW[ni][reg]);
            U[base2 + (size_t)row * 64 + col] = accU[ni][reg];
            Atb16[base2 + (size_t)row * 64 + col] =
                (col <= row) ? bf16c(accT[ni][reg]) : (short)0;
        }
    for (int e = tid; e < 512; e += 256) {
        int row = e >> 3, gl2 = e & 7;
        *(bf16x8*)&Kntb16[base2 + row * 64 + ((gl2 ^ (row & 7)) << 3)] =
            *(const bf16x8*)&knt[row * 64 + (gl2 << 3)];
    }
}

// ---------------- MFMA chunk scan: one block per (b,h,dv-quarter) -------------
#define LOADF(cc, F, UU) {                                                     \
    size_t tb_ = ((size_t)(bh * 16 + (cc))) * 4096;                            \
    F##0 = *(const bf16x8*)&Wb16[tb_ + off0];                                  \
    F##1 = *(const bf16x8*)&Wb16[tb_ + off1];                                  \
    F##2 = *(const bf16x8*)&Qsb16[tb_ + off0];                                 \
    F##3 = *(const bf16x8*)&Qsb16[tb_ + off1];                                 \
    F##4 = *(const bf16x8*)&Atb16[tb_ + off0];                                 \
    F##5 = *(const bf16x8*)&Atb16[tb_ + off1];                                 \
    F##6 = *(const bf16x8*)&Kntb16[tb_ + off0];                                \
    F##7 = *(const bf16x8*)&Kntb16[tb_ + off1];                                \
    UU##0 = U[tb_ + urow + 0 * 64]; UU##1 = U[tb_ + urow + 1 * 64];            \
    UU##2 = U[tb_ + urow + 2 * 64]; UU##3 = U[tb_ + urow + 3 * 64]; }

#define BODY(c, F, UU, FN, UN) {                                               \
    int cn_ = ((c) + 1 < 16) ? (c) + 1 : 0;                                    \
    LOADF(cn_, FN, UN);                                                        \
    bf16x8 st0 = *(const bf16x8*)&ST[stoff0];                                  \
    bf16x8 st1 = *(const bf16x8*)&ST[stoff1];                                  \
    bf16x8 nw0, nw1;                                                           \
    _Pragma("unroll") for (int t_ = 0; t_ < 8; ++t_) {                         \
        nw0[t_] = F##0[t_] ^ (short)0x8000;                                    \
        nw1[t_] = F##1[t_] ^ (short)0x8000; }                                  \
    f32x4 ut = {UU##0, UU##1, UU##2, UU##3};                                   \
    ut = __builtin_amdgcn_mfma_f32_16x16x32_bf16(nw0, st0, ut, 0, 0, 0);       \
    ut = __builtin_amdgcn_mfma_f32_16x16x32_bf16(nw1, st1, ut, 0, 0, 0);       \
    f32x4 o = (f32x4)0.f;                                                      \
    o = __builtin_amdgcn_mfma_f32_16x16x32_bf16(F##2, st0, o, 0, 0, 0);        \
    o = __builtin_amdgcn_mfma_f32_16x16x32_bf16(F##3, st1, o, 0, 0, 0);        \
    _Pragma("unroll") for (int j_ = 0; j_ < 4; ++j_) {                         \
        int rr_ = R0 + quad * 4 + j_;                                          \
        UT[l15 * 64 + (((rr_ >> 3) ^ (l15 & 7)) << 3) + (rr_ & 7)] = bf16c(ut[j_]); } \
    __syncthreads();                                                           \
    bf16x8 uf0 = *(const bf16x8*)&UT[stoff0];                                  \
    bf16x8 uf1 = *(const bf16x8*)&UT[stoff1];                                  \
    o = __builtin_amdgcn_mfma_f32_16x16x32_bf16(F##4, uf0, o, 0, 0, 0);        \
    o = __builtin_amdgcn_mfma_f32_16x16x32_bf16(F##5, uf1, o, 0, 0, 0);        \
    S = __builtin_amdgcn_mfma_f32_16x16x32_bf16(F##6, uf0, S, 0, 0, 0);        \
    S = __builtin_amdgcn_mfma_f32_16x16x32_bf16(F##7, uf1, S, 0, 0, 0);        \
    _Pragma("unroll") for (int j_ = 0; j_ < 4; ++j_)                           \
        deltab[obase + (size_t)((c) * 64 + j_) * 768] = bf16c(o[j_]);          \
    _Pragma("unroll") for (int j_ = 0; j_ < 4; ++j_) {                         \
        int dd_ = R0 + quad * 4 + j_;                                          \
        ST[l15 * 64 + (((dd_ >> 3) ^ (l15 & 7)) << 3) + (dd_ & 7)] = bf16c(S[j_]); } \
    __syncthreads(); }

__global__ __launch_bounds__(256) void scan_kernel(const short* __restrict__ Qsb16,
        const short* __restrict__ Kntb16, const float* __restrict__ U,
        const short* __restrict__ Wb16, const short* __restrict__ Atb16,
        short* __restrict__ deltab) {
    __shared__ short ST[1024];
    __shared__ short UT[1024];
    const int bh = blockIdx.x;
    const int b = bh / Hh, h = bh % Hh;
    const int g0 = blockIdx.y * 16;
    const int tid = threadIdx.x;
    const int lane = tid & 63, w = tid >> 6;
    const int quad = lane >> 4, l15 = lane & 15;
    const int R0 = w * 16;
    const int off0 = (R0 + l15) * 64 + quad * 8;
    const int off1 = off0 + 32;
    const int urow = (R0 + quad * 4) * 64 + g0 + l15;
    const int stoff0 = l15 * 64 + ((quad ^ (l15 & 7)) << 3);
    const int stoff1 = l15 * 64 + (((4 + quad) ^ (l15 & 7)) << 3);
    const size_t obase = ((size_t)(b * Nn + R0 + quad * 4)) * 768 + h * 64 + g0 + l15;

    for (int e = tid; e < 512; e += 256) ((int*)ST)[e] = 0;
    f32x4 S = (f32x4)0.f;
    bf16x8 fA0, fA1, fA2, fA3, fA4, fA5, fA6, fA7;
    bf16x8 fB0, fB1, fB2, fB3, fB4, fB5, fB6, fB7;
    float uA0, uA1, uA2, uA3, uB0, uB1, uB2, uB3;
    LOADF(0, fA, uA);
    __syncthreads();
#pragma unroll 1
    for (int c = 0; c < 16; c += 2) {
        BODY(c, fA, uA, fB, uB);
        BODY(c + 1, fB, uB, fA, uA);
    }
}

// ---------------- FIR + head-mix + prune softmax + gates + entropies ----------
__global__ __launch_bounds__(256) void paths_kernel(const short* __restrict__ qkvb,
        const short* __restrict__ deltab, const short* __restrict__ idoutb,
        const float* __restrict__ plig, const float* __restrict__ gl,
        const float* __restrict__ mixw, const float* __restrict__ idst,
        const float* __restrict__ firsT, const float* __restrict__ firlT,
        short* __restrict__ ctxb, float* __restrict__ entslots) {
    __shared__ float vt[10][768];
    __shared__ float fsb[768], flb[768];
    __shared__ float wts4[4][60], gate4[4][12], idg4[4][12];
    __shared__ float entb[48];
    const int blk = blockIdx.x;
    const int b = blk >> 8, n0 = (blk & 255) * 4;
    const int tid = threadIdx.x;

    // stage v rows n0-6 .. n0+3 (bf16 -> f32)
    for (int t = tid; t < 960; t += 256) {
        int row = t / 96, c8 = (t % 96) * 8;
        int np = n0 - 6 + row;
        float4 lo = make_float4(0.f, 0.f, 0.f, 0.f);
        float4 hi = make_float4(0.f, 0.f, 0.f, 0.f);
        if (np >= 0) {
            bf16x8 vv = *(const bf16x8*)&qkvb[((size_t)((b << 10) + np)) * 2304 + 1536 + c8];
            lo.x = b2f(vv[0]); lo.y = b2f(vv[1]); lo.z = b2f(vv[2]); lo.w = b2f(vv[3]);
            hi.x = b2f(vv[4]); hi.y = b2f(vv[5]); hi.z = b2f(vv[6]); hi.w = b2f(vv[7]);
        }
        *(float4*)&vt[row][c8] = lo;
        *(float4*)&vt[row][c8 + 4] = hi;
    }
    if (tid < 48) {
        int ni = tid / 12, h = tid % 12;
        int bn = (b << 10) + n0 + ni;
        const float* pb = &plig[(size_t)bn * 128];
        float lg[5]; float mx = -1e30f;
#pragma unroll
        for (int p = 0; p < 5; ++p) { lg[p] = pb[h * 5 + p]; mx = fmaxf(mx, lg[p]); }
        float sum = 0.f;
#pragma unroll
        for (int p = 0; p < 5; ++p) { lg[p] = __expf(lg[p] - mx); sum += lg[p]; }
        float e1 = 0.f;
#pragma unroll
        for (int p = 0; p < 5; ++p) {
            float wv = lg[p] / sum;
            wts4[ni][h * 5 + p] = wv;
            e1 += wv * logf(wv + 1e-8f);
        }
        float g = sigmoidf_(gl[(size_t)bn * 128 + h]);
        gate4[ni][h] = g;
        float e2 = g * logf(g + 1e-8f) + (1.f - g) * logf(1.f - g + 1e-8f);
        idg4[ni][h] = sigmoidf_(pb[60 + h]) * sigmoidf_(idst[h]);
        entb[tid] = e1 + e2;
    }
    float4 wl[7], wsv[3];
    if (tid < 192) {
        int c4 = tid * 4;
#pragma unroll
        for (int t = 0; t < 7; ++t) wl[t] = *(const float4*)&firlT[t * 768 + c4];
#pragma unroll
        for (int t = 0; t < 3; ++t) wsv[t] = *(const float4*)&firsT[t * 768 + c4];
    }
    __syncthreads();

#pragma unroll 1
    for (int ni = 0; ni < 4; ++ni) {
        if (tid < 192) {
            int c4 = tid * 4;
            float4 as = make_float4(0.f, 0.f, 0.f, 0.f);
            float4 al = make_float4(0.f, 0.f, 0.f, 0.f);
#pragma unroll
            for (int t = 0; t < 7; ++t) {
                float4 vv = *(const float4*)&vt[ni + t][c4];
                al.x += wl[t].x * vv.x; al.y += wl[t].y * vv.y;
                al.z += wl[t].z * vv.z; al.w += wl[t].w * vv.w;
                if (t >= 4) {
                    as.x += wsv[t - 4].x * vv.x; as.y += wsv[t - 4].y * vv.y;
                    as.z += wsv[t - 4].z * vv.z; as.w += wsv[t - 4].w * vv.w;
                }
            }
            *(float4*)&fsb[c4] = as;
            *(float4*)&flb[c4] = al;
        }
        __syncthreads();
        if (tid < 192) {
            int c4 = tid * 4;
            int h = c4 >> 6, d = c4 & 63;
            float4 ms = *(const float4*)&fsb[c4];
            float4 ml = *(const float4*)&flb[c4];
#pragma unroll
            for (int hh = 0; hh < 12; ++hh) {
                float mw = mixw[hh * 12 + h];
                float4 fsv = *(const float4*)&fsb[hh * 64 + d];
                float4 flv = *(const float4*)&flb[hh * 64 + d];
                ms.x += mw * fsv.x; ms.y += mw * fsv.y;
                ms.z += mw * fsv.z; ms.w += mw * fsv.w;
                ml.x += mw * flv.x; ml.y += mw * flv.y;
                ml.z += mw * flv.z; ml.w += mw * flv.w;
            }
            int bn = (b << 10) + n0 + ni;
            short4 ds = *(const short4*)&deltab[(size_t)bn * 768 + c4];
            short4 is = *(const short4*)&idoutb[(size_t)bn * 768 + c4];
            float4 vv = *(const float4*)&vt[ni + 6][c4];
            float ig = idg4[ni][h];
            const float* wp = &wts4[ni][h * 5];
            float4 pr;
            pr.x = ms.x * wp[0] + ml.x * wp[1] + b2f(ds.x) * wp[2] + vv.x * wp[3] + b2f(is.x) * ig * wp[4];
            pr.y = ms.y * wp[0] + ml.y * wp[1] + b2f(ds.y) * wp[2] + vv.y * wp[3] + b2f(is.y) * ig * wp[4];
            pr.z = ms.z * wp[0] + ml.z * wp[1] + b2f(ds.z) * wp[2] + vv.z * wp[3] + b2f(is.z) * ig * wp[4];
            pr.w = ms.w * wp[0] + ml.w * wp[1] + b2f(ds.w) * wp[2] + vv.w * wp[3] + b2f(is.w) * ig * wp[4];
            float g = gate4[ni][h];
            short4 o;
            o.x = bf16c(pr.x * g); o.y = bf16c(pr.y * g);
            o.z = bf16c(pr.z * g); o.w = bf16c(pr.w * g);
            *(short4*)&ctxb[(size_t)bn * 768 + c4] = o;
        }
        __syncthreads();
    }
    if (tid == 0) {
        float s = 0.f;
#pragma unroll
        for (int i = 0; i < 48; ++i) s += entb[i];
        entslots[blk] = s;
    }
}

extern "C" void kernel_launch(void* const* d_in, const int* in_sizes, int n_in,
                              void* d_out, int out_size, void* d_ws, size_t ws_size,
                              hipStream_t stream) {
    const float* x        = (const float*)d_in[0];
    const float* w_qkv    = (const float*)d_in[1];
    const float* w_proj   = (const float*)d_in[2];
    const float* b_proj   = (const float*)d_in[3];
    const float* fir_s_w  = (const float*)d_in[4];
    const float* fir_l_w  = (const float*)d_in[5];
    const float* mixw     = (const float*)d_in[6];
    const float* w_prune  = (const float*)d_in[7];
    const float* b_prune  = (const float*)d_in[8];
    const float* w_g1     = (const float*)d_in[9];
    const float* b_g1     = (const float*)d_in[10];
    const float* w_g2     = (const float*)d_in[11];
    const float* b_g2     = (const float*)d_in[12];
    const float* w_id     = (const float*)d_in[13];
    const float* id_st    = (const float*)d_in[14];
    const float* w_idgate = (const float*)d_in[15];
    const float* b_idgate = (const float*)d_in[16];
    float* out = (float*)d_out;
    float* ws  = (float*)d_ws;

    float* Ub    = ws + WS_U;
    float* plig  = ws + WS_PLIG;
    float* gl    = ws + WS_GL;
    float* ent   = ws + WS_ENT;
    float* firsT = ws + WS_FIRST;
    float* firlT = ws + WS_FIRLT;
    float* cbias = ws + WS_CBIAS;
    float* gbias = ws + WS_GBIAS;
    short* wsh   = (short*)(ws + WS_SH);
    short* xb      = wsh + SH_XB;
    short* qkvb    = wsh + SH_QKVB;
    short* idoutb  = wsh + SH_IDOUT;
    short* hdnb    = wsh + SH_HDNB;
    short* ctxb    = wsh + SH_CTXB;
    short* deltab  = wsh + SH_DELTA;
    short* Qsb16   = wsh + SH_QS;
    short* Kntb16  = wsh + SH_KNT;
    short* Wb16    = wsh + SH_W;
    short* Atb16   = wsh + SH_AT;
    short* wcat2T  = wsh + SH_WCAT2T;
    short* g2T     = wsh + SH_G2T;
    short* wprojT  = wsh + SH_WPROJT;

    // conversions + prep (z=4: small weights; z=5: x -> bf16)
    convert_w_kernel<<<dim3(12, 36, 6), 256, 0, stream>>>(w_qkv, w_id, w_g1, w_proj,
            wcat2T, wprojT, w_prune, w_idgate, b_prune, b_idgate, b_g1, b_g2,
            w_g2, fir_s_w, fir_l_w, g2T, cbias, gbias, firsT, firlT, x, xb);
    // fused main projection: qkv | idout | gelu-hdn | prune+idgate logits
    gemm_main<<<dim3(31, 32), 256, 0, stream>>>(xb, wcat2T, cbias,
                                                qkvb, idoutb, hdnb, plig);
    // delta-rule preprocessing (768 blocks) + gate GEMM (32 blocks), one launch
    pre_gl_kernel<<<dim3(800), 256, 0, stream>>>(qkvb, Qsb16, Kntb16, Ub, Wb16, Atb16,
                                                 hdnb, g2T, gbias, gl);
    // sequential chunk scan
    scan_kernel<<<dim3(BH, 4), 256, 0, stream>>>(Qsb16, Kntb16, Ub, Wb16, Atb16, deltab);
    // FIR + mix + prune + gates + entropies (writes bf16 context directly)
    paths_kernel<<<dim3(1024), 256, 0, stream>>>(qkvb, deltab, idoutb, plig, gl,
                                                 mixw, id_st, firsT, firlT, ctxb, ent);
    // output projection + fused entropy finalize (block 0)
    gemm_mfma<<<dim3(6, 32), 256, 0, stream>>>(ctxb, wprojT, b_proj, out, BN, 768, 768,
                                               ent, out + OUT_ELEMS);
}

// Round 12
// 244.950 us; speedup vs baseline: 1.0758x; 1.0758x over previous
//
#include <hip/hip_runtime.h>
#include <hip/hip_bf16.h>
#include <math.h>

// Problem dims (fixed by setup_inputs)
#define Bz 4
#define Nn 1024
#define Cc 768
#define Hh 12
#define Dd 64
#define BN 4096          // B*N
#define NC 16            // chunks per sequence
#define BH 48            // B*H
#define OUT_ELEMS 3145728  // BN*C

// ---------------- workspace layout ----------------
// float offsets:
#define WS_U       0u          // f32 [768 tiles][4096]
#define WS_PLIG    3145728u    // f32 [BN][128] (72 used: prune60|idgate12)
#define WS_GL      3670016u    // f32 [BN][128] (12 used)
#define WS_ENT     4194304u    // [1024]
#define WS_FIRST   4195328u    // [3][768]
#define WS_FIRLT   4197632u    // [7][768]
#define WS_CBIAS   4203008u    // [3968]
#define WS_GBIAS   4206976u    // [128]
#define WS_SH      4207104u    // shorts region starts here (float offset)
// short offsets within the bf16 region:
#define SH_XB      0u          // [BN][768]
#define SH_QKVB    3145728u    // [BN][2304]
#define SH_IDOUT   12582912u   // [BN][768]
#define SH_HDNB    15728640u   // [BN][768]
#define SH_CTXB    18874368u   // [BN][768]
#define SH_DELTA   22020096u   // [BN][768]
#define SH_QS      25165824u   // [768 tiles][4096]
#define SH_KNT     28311552u
#define SH_W       31457280u
#define SH_AT      34603008u
#define SH_WCAT2T  37748736u   // [3968][768]: wqkvT|w_idT|w_g1T|wcombT(72)+pad
#define SH_G2T     40796160u   // [128][768]
#define SH_WPROJT  40894464u   // [768][768]

typedef __attribute__((ext_vector_type(8))) short bf16x8;
typedef __attribute__((ext_vector_type(4))) float f32x4;

__device__ __forceinline__ float sigmoidf_(float x) { return 1.f / (1.f + __expf(-x)); }
__device__ __forceinline__ float geluf_(float x) {
    float t = tanhf(0.7978845608028654f * (x + 0.044715f * x * x * x));
    return 0.5f * x * (1.f + t);
}
__device__ __forceinline__ short bf16c(float f) {
    union { float f; unsigned u; } a; a.f = f;
    unsigned r = a.u + 0x7fffu + ((a.u >> 16) & 1u);
    return (short)(r >> 16);
}
__device__ __forceinline__ float b2f(short s) {
    union { float f; unsigned u; } a;
    a.u = ((unsigned)(unsigned short)s) << 16;
    return a.f;
}
__device__ __forceinline__ void gload16(const void* g, void* l) {
    __builtin_amdgcn_global_load_lds(
        (const __attribute__((address_space(1))) unsigned*)g,
        (__attribute__((address_space(3))) unsigned*)l, 16, 0, 0);
}
// MFMA fragment read from a 64x64 bf16 LDS array with per-row XOR granule swizzle.
__device__ __forceinline__ bf16x8 frag_(const short* arr, int row, int kc, int quad) {
    return *(const bf16x8*)&arr[row * 64 + (((kc * 4 + quad) ^ (row & 7)) << 3)];
}

// -------- weight transpose + bf16 convert (z=0..3) + prep (z=4) + x (z=5) ----
__global__ __launch_bounds__(256) void convert_w_kernel(const float* __restrict__ w_qkv,
        const float* __restrict__ w_id, const float* __restrict__ w_g1,
        const float* __restrict__ w_proj, short* __restrict__ wcat2T,
        short* __restrict__ wprojT,
        const float* __restrict__ wp, const float* __restrict__ wig,
        const float* __restrict__ bp, const float* __restrict__ big,
        const float* __restrict__ bg1, const float* __restrict__ bg2,
        const float* __restrict__ wg2, const float* __restrict__ firs,
        const float* __restrict__ firl, short* __restrict__ g2T,
        float* __restrict__ cbias, float* __restrict__ gbias,
        float* __restrict__ firsT, float* __restrict__ firlT,
        const float* __restrict__ x, short* __restrict__ xb) {
    __shared__ float t[64][65];
    const int z = blockIdx.z;
    const int tid = threadIdx.x;
    if (z == 5) {
        for (int i = (blockIdx.y * 12 + blockIdx.x) * 256 + tid; i < 786432;
             i += 110592) {
            float4 v = *(const float4*)&x[(size_t)i * 4];
            short4 o;
            o.x = bf16c(v.x); o.y = bf16c(v.y); o.z = bf16c(v.z); o.w = bf16c(v.w);
            *(short4*)&xb[(size_t)i * 4] = o;
        }
        return;
    }
    if (z == 4) {
        int i = (blockIdx.y * 12 + blockIdx.x) * 256 + tid;
        if (i < 98304) {
            int r = i / 768, k = i % 768;
            float wv = 0.f;
            if (r < 60) wv = wp[k * 60 + r];
            else if (r < 72) wv = wig[k * 12 + (r - 60)];
            wcat2T[(size_t)(3840 + r) * 768 + k] = (r < 72) ? bf16c(wv) : (short)0;
            g2T[(size_t)r * 768 + k] = (r < 12) ? bf16c(wg2[k * 12 + r]) : (short)0;
        }
        if (i < 3968) {
            float bv = 0.f;
            if (i >= 3072 && i < 3840) bv = bg1[i - 3072];
            else if (i >= 3840 && i < 3900) bv = bp[i - 3840];
            else if (i >= 3900 && i < 3912) bv = big[i - 3900];
            cbias[i] = bv;
        }
        if (i < 128) gbias[i] = (i < 12) ? bg2[i] : 0.f;
        if (i < 2304) { int tt = i / 768, e = i % 768; firsT[tt * 768 + e] = firs[e * 3 + tt]; }
        if (i < 5376) { int tt = i / 768, e = i % 768; firlT[tt * 768 + e] = firl[e * 7 + tt]; }
        return;
    }
    const float* src; short* dst; int Nw;
    if (z == 0)      { src = w_qkv;  dst = wcat2T;               Nw = 2304; }
    else if (z == 1) { src = w_id;   dst = wcat2T + 2304 * 768;  Nw = 768; }
    else if (z == 2) { src = w_g1;   dst = wcat2T + 3072 * 768;  Nw = 768; }
    else             { src = w_proj; dst = wprojT;               Nw = 768; }
    const int n0 = blockIdx.y * 64;
    if (n0 >= Nw) return;
    const int k0 = blockIdx.x * 64;
    for (int e = tid; e < 1024; e += 256) {
        int r = e >> 4, c4 = (e & 15) * 4;
        float4 v = *(const float4*)&src[(size_t)(k0 + r) * Nw + n0 + c4];
        t[c4 + 0][r] = v.x; t[c4 + 1][r] = v.y;
        t[c4 + 2][r] = v.z; t[c4 + 3][r] = v.w;
    }
    __syncthreads();
    for (int e = tid; e < 1024; e += 256) {
        int r = e >> 4, c4 = (e & 15) * 4;
        short4 o;
        o.x = bf16c(t[r][c4 + 0]); o.y = bf16c(t[r][c4 + 1]);
        o.z = bf16c(t[r][c4 + 2]); o.w = bf16c(t[r][c4 + 3]);
        *(short4*)&dst[(size_t)(n0 + r) * 768 + k0 + c4] = o;
    }
}

// ---------------- shared MFMA K-loop core (128x64 tile, BK=64) ---------------
// Smaller tile than the classic 128x128: LDS 24KB (6 blocks/CU), acc 32 VGPR,
// 2x the block count -- more TLP to hide the per-iteration barrier-drained
// L2/L3 latency (R11: 128x128 ran at 18% occupancy, latency-bound at 5x its
// BW floor). Per-output MFMA k-order identical -> bit-identical results.
// XCD swizzle (blocks%8==0): L -> xcd=L&7, rowmod=(L>>3)&3, col=L>>5;
// XCD x owns compact rows 4x..4x+3 (A strips L2-resident), B streamed.
// NOTE (R9): do NOT register-stage prefetch here -- it spills and regresses.
#define GEMM_CORE(APTR, BPTR, KDIM)                                            \
    __shared__ short As[128 * 64];                                             \
    __shared__ short Bs[64 * 64];                                              \
    const int tid = threadIdx.x;                                               \
    const int lane = tid & 63, w = tid >> 6;                                   \
    const int quad = lane >> 4, l15 = lane & 15;                               \
    const int L_ = blockIdx.y * gridDim.x + blockIdx.x;                        \
    const int xcd_ = L_ & 7, j_ = L_ >> 3;                                     \
    const int row0 = (xcd_ * 4 + (j_ & 3)) * 128, col0 = (j_ >> 2) * 64;       \
    const int wm = (w >> 1) * 64, wn = (w & 1) * 32;                           \
    int srow[4]; int scol[4]; int brow[2]; int bcol[2];                        \
    _Pragma("unroll") for (int i = 0; i < 4; ++i) {                            \
        int G = (w * 4 + i) * 64 + lane;                                       \
        int row = G >> 3, g = G & 7;                                           \
        srow[i] = row;                                                         \
        scol[i] = (g ^ (row & 7)) * 8;                                         \
    }                                                                          \
    _Pragma("unroll") for (int i = 0; i < 2; ++i) {                            \
        int G = (w * 2 + i) * 64 + lane;                                       \
        int row = G >> 3, g = G & 7;                                           \
        brow[i] = row;                                                         \
        bcol[i] = (g ^ (row & 7)) * 8;                                         \
    }                                                                          \
    int aoff[4][2], boff[2][2];                                                \
    _Pragma("unroll") for (int mi = 0; mi < 4; ++mi)                           \
        _Pragma("unroll") for (int kk = 0; kk < 2; ++kk) {                     \
            int ra = wm + mi * 16 + l15;                                       \
            aoff[mi][kk] = ra * 128 + (((kk * 4 + quad) ^ (ra & 7)) * 16);     \
        }                                                                      \
    _Pragma("unroll") for (int ni = 0; ni < 2; ++ni)                           \
        _Pragma("unroll") for (int kk = 0; kk < 2; ++kk) {                     \
            int rb = wn + ni * 16 + l15;                                       \
            boff[ni][kk] = rb * 128 + (((kk * 4 + quad) ^ (rb & 7)) * 16);     \
        }                                                                      \
    f32x4 acc[4][2];                                                           \
    _Pragma("unroll") for (int mi = 0; mi < 4; ++mi)                           \
        _Pragma("unroll") for (int ni = 0; ni < 2; ++ni) acc[mi][ni] = (f32x4)0.f; \
    for (int k0 = 0; k0 < (KDIM); k0 += 64) {                                  \
        _Pragma("unroll") for (int i = 0; i < 4; ++i)                          \
            gload16(&(APTR)[(size_t)(row0 + srow[i]) * (KDIM) + k0 + scol[i]], \
                    &As[(w * 4 + i) * 512]);                                   \
        _Pragma("unroll") for (int i = 0; i < 2; ++i)                          \
            gload16(&(BPTR)[(size_t)(col0 + brow[i]) * (KDIM) + k0 + bcol[i]], \
                    &Bs[(w * 2 + i) * 512]);                                   \
        __syncthreads();                                                       \
        _Pragma("unroll") for (int kk = 0; kk < 2; ++kk) {                     \
            bf16x8 af[4], bfr[2];                                              \
            _Pragma("unroll") for (int mi = 0; mi < 4; ++mi)                   \
                af[mi] = *(const bf16x8*)((const char*)As + aoff[mi][kk]);     \
            _Pragma("unroll") for (int ni = 0; ni < 2; ++ni)                   \
                bfr[ni] = *(const bf16x8*)((const char*)Bs + boff[ni][kk]);    \
            _Pragma("unroll") for (int mi = 0; mi < 4; ++mi)                   \
                _Pragma("unroll") for (int ni = 0; ni < 2; ++ni)               \
                    acc[mi][ni] = __builtin_amdgcn_mfma_f32_16x16x32_bf16(     \
                        af[mi], bfr[ni], acc[mi][ni], 0, 0, 0);                \
        }                                                                      \
        __syncthreads();                                                       \
    }

// ---------------- fused main projection: x @ [wqkv|w_id|w_g1|wcomb] ----------
// N=3968 (62 col-tiles x 32 row-tiles = 1984 blocks).
__global__ __launch_bounds__(256) void gemm_main(const short* __restrict__ A,
        const short* __restrict__ BT, const float* __restrict__ bias,
        short* __restrict__ qkvb, short* __restrict__ idoutb,
        short* __restrict__ hdnb, float* __restrict__ plig) {
    GEMM_CORE(A, BT, 768)
#pragma unroll
    for (int ni = 0; ni < 2; ++ni) {
        int col = col0 + wn + ni * 16 + l15;
        float bv = bias[col];
#pragma unroll
        for (int mi = 0; mi < 4; ++mi) {
#pragma unroll
            for (int r = 0; r < 4; ++r) {
                int row = row0 + wm + mi * 16 + quad * 4 + r;
                float v = acc[mi][ni][r] + bv;
                if (col < 2304) {
                    qkvb[(size_t)row * 2304 + col] = bf16c(v);
                } else if (col < 3072) {
                    idoutb[(size_t)row * 768 + (col - 2304)] = bf16c(v);
                } else if (col < 3840) {
                    hdnb[(size_t)row * 768 + (col - 3072)] = bf16c(geluf_(v));
                } else {
                    plig[(size_t)row * 128 + (col - 3840)] = v;
                }
            }
        }
    }
}

// -------- generic bf16 MFMA GEMM (+ optional fused entropy finalize) ---------
__global__ __launch_bounds__(256) void gemm_mfma(const short* __restrict__ A,
        const short* __restrict__ BT, const float* __restrict__ bias,
        float* __restrict__ C, int M, int N, int K,
        const float* __restrict__ slots, float* __restrict__ entout) {
    __shared__ float red[256];
    GEMM_CORE(A, BT, K)
#pragma unroll
    for (int ni = 0; ni < 2; ++ni) {
        int col = col0 + wn + ni * 16 + l15;
        float bv = bias ? bias[col] : 0.f;
#pragma unroll
        for (int mi = 0; mi < 4; ++mi) {
#pragma unroll
            for (int r = 0; r < 4; ++r) {
                int row = row0 + wm + mi * 16 + quad * 4 + r;
                C[(size_t)row * N + col] = acc[mi][ni][r] + bv;
            }
        }
    }
    if (slots && L_ == 0) {
        float s = 0.f;
        for (int i = tid; i < 1024; i += 256) s += slots[i];
        red[tid] = s;
        __syncthreads();
        for (int off = 128; off > 0; off >>= 1) {
            if (tid < off) red[tid] += red[tid + off];
            __syncthreads();
        }
        if (tid == 0) entout[0] = -red[0] * (1.f / 49152.f);
    }
}

// ------- gate GEMM (blocks 0..31) + delta-rule preprocessing (32..799) -------
// gl blocks FIRST: with 50KB LDS only 3 blocks/CU (768 slots) are resident;
// putting the 32 gl blocks at the tail serialized them after pre (R11 bug).
__global__ __launch_bounds__(256) void pre_gl_kernel(const short* __restrict__ qkvb,
        short* __restrict__ Qsb16, short* __restrict__ Kntb16, float* __restrict__ U,
        short* __restrict__ Wb16, short* __restrict__ Atb16,
        const short* __restrict__ hdnb, const short* __restrict__ g2T,
        const float* __restrict__ gbias, float* __restrict__ gl) {
    __shared__ __align__(16) char smem[50176];
    const int blk = blockIdx.x;
    const int tid = threadIdx.x;
    const int lane = tid & 63, w = tid >> 6;
    const int quad = lane >> 4, l15 = lane & 15;

    if (blk < 32) {
        // ---- gate GEMM: 128x128 tile, row0 = blk*128, col0 = 0, K = 768 ----
        short* As = (short*)smem;
        short* Bs = (short*)(smem + 16384);
        const int row0 = blk * 128;
        const int wm = (w >> 1) * 64, wn = (w & 1) * 64;
        int srow[4], scol[4];
#pragma unroll
        for (int i = 0; i < 4; ++i) {
            int G = (w * 4 + i) * 64 + lane;
            int row = G >> 3, g = G & 7;
            srow[i] = row;
            scol[i] = (g ^ (row & 7)) * 8;
        }
        int aoff[4][2], boff[4][2];
#pragma unroll
        for (int mi = 0; mi < 4; ++mi)
#pragma unroll
            for (int kk = 0; kk < 2; ++kk) {
                int ra = wm + mi * 16 + l15;
                aoff[mi][kk] = ra * 128 + (((kk * 4 + quad) ^ (ra & 7)) * 16);
                int rb = wn + mi * 16 + l15;
                boff[mi][kk] = rb * 128 + (((kk * 4 + quad) ^ (rb & 7)) * 16);
            }
        f32x4 acc[4][4];
#pragma unroll
        for (int mi = 0; mi < 4; ++mi)
#pragma unroll
            for (int ni = 0; ni < 4; ++ni) acc[mi][ni] = (f32x4)0.f;
        for (int k0 = 0; k0 < 768; k0 += 64) {
#pragma unroll
            for (int i = 0; i < 4; ++i) {
                gload16(&hdnb[(size_t)(row0 + srow[i]) * 768 + k0 + scol[i]],
                        &As[(w * 4 + i) * 512]);
                gload16(&g2T[(size_t)srow[i] * 768 + k0 + scol[i]],
                        &Bs[(w * 4 + i) * 512]);
            }
            __syncthreads();
#pragma unroll
            for (int kk = 0; kk < 2; ++kk) {
                bf16x8 af[4], bfr[4];
#pragma unroll
                for (int mi = 0; mi < 4; ++mi)
                    af[mi] = *(const bf16x8*)((const char*)As + aoff[mi][kk]);
#pragma unroll
                for (int ni = 0; ni < 4; ++ni)
                    bfr[ni] = *(const bf16x8*)((const char*)Bs + boff[ni][kk]);
#pragma unroll
                for (int mi = 0; mi < 4; ++mi)
#pragma unroll
                    for (int ni = 0; ni < 4; ++ni)
                        acc[mi][ni] = __builtin_amdgcn_mfma_f32_16x16x32_bf16(
                            af[mi], bfr[ni], acc[mi][ni], 0, 0, 0);
            }
            __syncthreads();
        }
#pragma unroll
        for (int ni = 0; ni < 4; ++ni) {
            int col = wn + ni * 16 + l15;
            float bv = gbias[col];
#pragma unroll
            for (int mi = 0; mi < 4; ++mi)
#pragma unroll
                for (int r = 0; r < 4; ++r) {
                    int row = row0 + wm + mi * 16 + quad * 4 + r;
                    gl[(size_t)row * 128 + col] = acc[mi][ni][r] + bv;
                }
        }
        return;
    }

    // ---------------- pre body (blocks 32..799) ----------------
    const int pblk = blk - 32;
    float (*ts)[68] = (float (*)[68])smem;               // 17408 B
    short* kn  = (short*)(smem + 17408);                 // 8192 B
    short* knt = (short*)(smem + 25600);                 // 8192 B
    short* qsb = (short*)(smem + 33792);                 // 8192 B
    short* vtb = (short*)(smem + 41984);                 // 8192 B
    float (*zbuf)[68] = (float (*)[68])(smem + 17408);   // overlays kn (dead after B)
    short* tb  = (short*)(smem + 33792);                 // overlays qsb (dead after B)
    const int c = pblk & 15, bh = pblk >> 4;
    const int b = bh / Hh, h = bh % Hh;
    const int r = tid >> 2, d0 = (tid & 3) * 16;
    const size_t rowb = ((size_t)(b * Nn + c * 64)) * 2304 + h * 64;
    const size_t base2 = (size_t)pblk * 4096;

    // ---- Phase A: bf16 loads; k-norm; fill LDS; Qsb16 straight to global ----
    {
        const short* qp = &qkvb[rowb + (size_t)r * 2304 + d0];
        bf16x8 qb0 = *(const bf16x8*)&qp[0],    qb1 = *(const bf16x8*)&qp[8];
        bf16x8 kb0 = *(const bf16x8*)&qp[768],  kb1 = *(const bf16x8*)&qp[776];
        bf16x8 vb0 = *(const bf16x8*)&qp[1536], vb1 = *(const bf16x8*)&qp[1544];

        float kf[16];
#pragma unroll
        for (int t = 0; t < 8; ++t) { kf[t] = b2f(kb0[t]); kf[8 + t] = b2f(kb1[t]); }
        float ss = 0.f;
#pragma unroll
        for (int t = 0; t < 16; ++t) ss += kf[t] * kf[t];
        ss += __shfl_xor(ss, 1);
        ss += __shfl_xor(ss, 2);
        float invn = 1.f / (sqrtf(ss) + 1e-6f);
        {
            bf16x8 g0, g1;
#pragma unroll
            for (int t = 0; t < 8; ++t) {
                g0[t] = bf16c(kf[t] * invn); g1[t] = bf16c(kf[8 + t] * invn);
            }
            int gb = d0 >> 3;
            *(bf16x8*)&kn[r * 64 + (((gb + 0) ^ (r & 7)) << 3)] = g0;
            *(bf16x8*)&kn[r * 64 + (((gb + 1) ^ (r & 7)) << 3)] = g1;
#pragma unroll
            for (int t = 0; t < 8; ++t) {
                int d = d0 + t;
                knt[d * 64 + (((r >> 3) ^ (d & 7)) << 3) + (r & 7)] = g0[t];
                int d2 = d0 + 8 + t;
                knt[d2 * 64 + (((r >> 3) ^ (d2 & 7)) << 3) + (r & 7)] = g1[t];
            }
        }
        {
            bf16x8 g0, g1;
#pragma unroll
            for (int t = 0; t < 8; ++t) {
                g0[t] = bf16c(b2f(qb0[t]) * 0.125f);
                g1[t] = bf16c(b2f(qb1[t]) * 0.125f);
            }
            int gb = d0 >> 3;
            *(bf16x8*)&qsb[r * 64 + (((gb + 0) ^ (r & 7)) << 3)] = g0;
            *(bf16x8*)&qsb[r * 64 + (((gb + 1) ^ (r & 7)) << 3)] = g1;
            *(bf16x8*)&Qsb16[base2 + r * 64 + d0] = g0;
            *(bf16x8*)&Qsb16[base2 + r * 64 + d0 + 8] = g1;
        }
#pragma unroll
        for (int t = 0; t < 8; ++t) {
            int d = d0 + t;
            vtb[d * 64 + (((r >> 3) ^ (d & 7)) << 3) + (r & 7)] = vb0[t];
            int d2 = d0 + 8 + t;
            vtb[d2 * 64 + (((r >> 3) ^ (d2 & 7)) << 3) + (r & 7)] = vb1[t];
        }
    }
    __syncthreads();

    // ---- Phase B: A_full = Kn Kn^T -> ts (tril,-1); accT = Qs Kn^T in regs ---
    f32x4 accT[4];
    {
        const int ar = w * 16 + l15;
        bf16x8 aK0 = frag_(kn, ar, 0, quad), aK1 = frag_(kn, ar, 1, quad);
        bf16x8 aQ0 = frag_(qsb, ar, 0, quad), aQ1 = frag_(qsb, ar, 1, quad);
        f32x4 accA[4];
#pragma unroll
        for (int ni = 0; ni < 4; ++ni) {
            int br = ni * 16 + l15;
            bf16x8 b0 = frag_(kn, br, 0, quad), b1 = frag_(kn, br, 1, quad);
            accA[ni] = __builtin_amdgcn_mfma_f32_16x16x32_bf16(aK0, b0, (f32x4)0.f, 0, 0, 0);
            accA[ni] = __builtin_amdgcn_mfma_f32_16x16x32_bf16(aK1, b1, accA[ni], 0, 0, 0);
            accT[ni] = __builtin_amdgcn_mfma_f32_16x16x32_bf16(aQ0, b0, (f32x4)0.f, 0, 0, 0);
            accT[ni] = __builtin_amdgcn_mfma_f32_16x16x32_bf16(aQ1, b1, accT[ni], 0, 0, 0);
        }
#pragma unroll
        for (int ni = 0; ni < 4; ++ni)
#pragma unroll
            for (int reg = 0; reg < 4; ++reg) {
                int row = w * 16 + quad * 4 + reg;
                int col = ni * 16 + l15;
                ts[row][col] = (col < row) ? accA[ni][reg] : 0.f;
            }
    }
    __syncthreads();

    // ---- Phase C1: 4 diagonal 16x16 unit-lower inversions, one per wave ------
    {
        const int R0 = w * 16;
        const int j = lane & 15, s = lane >> 4;
#pragma unroll 1
        for (int i = 0; i < 16; ++i) {
            float p = 0.f;
            for (int m = s; m < i; m += 4)
                p += ts[R0 + i][R0 + m] * ts[R0 + m][R0 + j];
            p += __shfl_xor(p, 16);
            p += __shfl_xor(p, 32);
            if (s == 0) ts[R0 + i][R0 + j] = ((j == i) ? 1.f : 0.f) - p;
        }
    }
    __syncthreads();
    // ---- Phase C2: off-diagonal block rows I=1..3 ----
#pragma unroll 1
    for (int I = 1; I < 4; ++I) {
        const int ncol = I * 16;
        for (int e = tid; e < 16 * ncol; e += 256) {
            int i = e / ncol, jj = e % ncol;
            float s = 0.f;
            for (int m = jj; m < ncol; ++m) s += ts[ncol + i][m] * ts[m][jj];
            zbuf[i][jj] = s;
        }
        __syncthreads();
        for (int e = tid; e < 16 * ncol; e += 256) {
            int i = e / ncol, jj = e % ncol;
            float s = 0.f;
            for (int ml = 0; ml <= i; ++ml) s += ts[ncol + i][ncol + ml] * zbuf[ml][jj];
            ts[ncol + i][jj] = -s;
        }
        __syncthreads();
    }
    // ---- convert T -> bf16 tb (qsb overlay) ----
    for (int e = tid; e < 512; e += 256) {
        int row = e >> 3, g = e & 7;
        bf16x8 o;
#pragma unroll
        for (int t = 0; t < 8; ++t) o[t] = bf16c(ts[row][g * 8 + t]);
        *(bf16x8*)&tb[row * 64 + ((g ^ (row & 7)) << 3)] = o;
    }
    __syncthreads();

    // ---- Phase D: W = T@Kn, U = T@V ----
    f32x4 accW[4], accU[4];
    {
        const int ar = w * 16 + l15;
        bf16x8 aT0 = frag_(tb, ar, 0, quad), aT1 = frag_(tb, ar, 1, quad);
#pragma unroll
        for (int ni = 0; ni < 4; ++ni) {
            int br = ni * 16 + l15;
            bf16x8 b0 = frag_(knt, br, 0, quad), b1 = frag_(knt, br, 1, quad);
            bf16x8 c0 = frag_(vtb, br, 0, quad), c1 = frag_(vtb, br, 1, quad);
            accW[ni] = __builtin_amdgcn_mfma_f32_16x16x32_bf16(aT0, b0, (f32x4)0.f, 0, 0, 0);
            accW[ni] = __builtin_amdgcn_mfma_f32_16x16x32_bf16(aT1, b1, accW[ni], 0, 0, 0);
            accU[ni] = __builtin_amdgcn_mfma_f32_16x16x32_bf16(aT0, c0, (f32x4)0.f, 0, 0, 0);
            accU[ni] = __builtin_amdgcn_mfma_f32_16x16x32_bf16(aT1, c1, accU[ni], 0, 0, 0);
        }
    }
    // ---- Tail: all remaining global stores ----
#pragma unroll
    for (int ni = 0; ni < 4; ++ni)
#pragma unroll
        for (int reg = 0; reg < 4; ++reg) {
            int row = w * 16 + quad * 4 + reg;
            int col = ni * 16 + l15;
            Wb16[base2 + (size_t)row * 64 + col] = bf16c(accW[ni][reg]);
            U[base2 + (size_t)row * 64 + col] = accU[ni][reg];
            Atb16[base2 + (size_t)row * 64 + col] =
                (col <= row) ? bf16c(accT[ni][reg]) : (short)0;
        }
    for (int e = tid; e < 512; e += 256) {
        int row = e >> 3, gl2 = e & 7;
        *(bf16x8*)&Kntb16[base2 + row * 64 + ((gl2 ^ (row & 7)) << 3)] =
            *(const bf16x8*)&knt[row * 64 + (gl2 << 3)];
    }
}

// ---------------- MFMA chunk scan: one block per (b,h,dv-quarter) -------------
#define LOADF(cc, F, UU) {                                                     \
    size_t tb_ = ((size_t)(bh * 16 + (cc))) * 4096;                            \
    F##0 = *(const bf16x8*)&Wb16[tb_ + off0];                                  \
    F##1 = *(const bf16x8*)&Wb16[tb_ + off1];                                  \
    F##2 = *(const bf16x8*)&Qsb16[tb_ + off0];                                 \
    F##3 = *(const bf16x8*)&Qsb16[tb_ + off1];                                 \
    F##4 = *(const bf16x8*)&Atb16[tb_ + off0];                                 \
    F##5 = *(const bf16x8*)&Atb16[tb_ + off1];                                 \
    F##6 = *(const bf16x8*)&Kntb16[tb_ + off0];                                \
    F##7 = *(const bf16x8*)&Kntb16[tb_ + off1];                                \
    UU##0 = U[tb_ + urow + 0 * 64]; UU##1 = U[tb_ + urow + 1 * 64];            \
    UU##2 = U[tb_ + urow + 2 * 64]; UU##3 = U[tb_ + urow + 3 * 64]; }

#define BODY(c, F, UU, FN, UN) {                                               \
    int cn_ = ((c) + 1 < 16) ? (c) + 1 : 0;                                    \
    LOADF(cn_, FN, UN);                                                        \
    bf16x8 st0 = *(const bf16x8*)&ST[stoff0];                                  \
    bf16x8 st1 = *(const bf16x8*)&ST[stoff1];                                  \
    bf16x8 nw0, nw1;                                                           \
    _Pragma("unroll") for (int t_ = 0; t_ < 8; ++t_) {                         \
        nw0[t_] = F##0[t_] ^ (short)0x8000;                                    \
        nw1[t_] = F##1[t_] ^ (short)0x8000; }                                  \
    f32x4 ut = {UU##0, UU##1, UU##2, UU##3};                                   \
    ut = __builtin_amdgcn_mfma_f32_16x16x32_bf16(nw0, st0, ut, 0, 0, 0);       \
    ut = __builtin_amdgcn_mfma_f32_16x16x32_bf16(nw1, st1, ut, 0, 0, 0);       \
    f32x4 o = (f32x4)0.f;                                                      \
    o = __builtin_amdgcn_mfma_f32_16x16x32_bf16(F##2, st0, o, 0, 0, 0);        \
    o = __builtin_amdgcn_mfma_f32_16x16x32_bf16(F##3, st1, o, 0, 0, 0);        \
    _Pragma("unroll") for (int j_ = 0; j_ < 4; ++j_) {                         \
        int rr_ = R0 + quad * 4 + j_;                                          \
        UT[l15 * 64 + (((rr_ >> 3) ^ (l15 & 7)) << 3) + (rr_ & 7)] = bf16c(ut[j_]); } \
    __syncthreads();                                                           \
    bf16x8 uf0 = *(const bf16x8*)&UT[stoff0];                                  \
    bf16x8 uf1 = *(const bf16x8*)&UT[stoff1];                                  \
    o = __builtin_amdgcn_mfma_f32_16x16x32_bf16(F##4, uf0, o, 0, 0, 0);        \
    o = __builtin_amdgcn_mfma_f32_16x16x32_bf16(F##5, uf1, o, 0, 0, 0);        \
    S = __builtin_amdgcn_mfma_f32_16x16x32_bf16(F##6, uf0, S, 0, 0, 0);        \
    S = __builtin_amdgcn_mfma_f32_16x16x32_bf16(F##7, uf1, S, 0, 0, 0);        \
    _Pragma("unroll") for (int j_ = 0; j_ < 4; ++j_)                           \
        deltab[obase + (size_t)((c) * 64 + j_) * 768] = bf16c(o[j_]);          \
    _Pragma("unroll") for (int j_ = 0; j_ < 4; ++j_) {                         \
        int dd_ = R0 + quad * 4 + j_;                                          \
        ST[l15 * 64 + (((dd_ >> 3) ^ (l15 & 7)) << 3) + (dd_ & 7)] = bf16c(S[j_]); } \
    __syncthreads(); }

__global__ __launch_bounds__(256) void scan_kernel(const short* __restrict__ Qsb16,
        const short* __restrict__ Kntb16, const float* __restrict__ U,
        const short* __restrict__ Wb16, const short* __restrict__ Atb16,
        short* __restrict__ deltab) {
    __shared__ short ST[1024];
    __shared__ short UT[1024];
    const int bh = blockIdx.x;
    const int b = bh / Hh, h = bh % Hh;
    const int g0 = blockIdx.y * 16;
    const int tid = threadIdx.x;
    const int lane = tid & 63, w = tid >> 6;
    const int quad = lane >> 4, l15 = lane & 15;
    const int R0 = w * 16;
    const int off0 = (R0 + l15) * 64 + quad * 8;
    const int off1 = off0 + 32;
    const int urow = (R0 + quad * 4) * 64 + g0 + l15;
    const int stoff0 = l15 * 64 + ((quad ^ (l15 & 7)) << 3);
    const int stoff1 = l15 * 64 + (((4 + quad) ^ (l15 & 7)) << 3);
    const size_t obase = ((size_t)(b * Nn + R0 + quad * 4)) * 768 + h * 64 + g0 + l15;

    for (int e = tid; e < 512; e += 256) ((int*)ST)[e] = 0;
    f32x4 S = (f32x4)0.f;
    bf16x8 fA0, fA1, fA2, fA3, fA4, fA5, fA6, fA7;
    bf16x8 fB0, fB1, fB2, fB3, fB4, fB5, fB6, fB7;
    float uA0, uA1, uA2, uA3, uB0, uB1, uB2, uB3;
    LOADF(0, fA, uA);
    __syncthreads();
#pragma unroll 1
    for (int c = 0; c < 16; c += 2) {
        BODY(c, fA, uA, fB, uB);
        BODY(c + 1, fB, uB, fA, uA);
    }
}

// ---------------- FIR + head-mix + prune softmax + gates + entropies ----------
__global__ __launch_bounds__(256) void paths_kernel(const short* __restrict__ qkvb,
        const short* __restrict__ deltab, const short* __restrict__ idoutb,
        const float* __restrict__ plig, const float* __restrict__ gl,
        const float* __restrict__ mixw, const float* __restrict__ idst,
        const float* __restrict__ firsT, const float* __restrict__ firlT,
        short* __restrict__ ctxb, float* __restrict__ entslots) {
    __shared__ float vt[10][768];
    __shared__ float fsb[768], flb[768];
    __shared__ float wts4[4][60], gate4[4][12], idg4[4][12];
    __shared__ float entb[48];
    const int blk = blockIdx.x;
    const int b = blk >> 8, n0 = (blk & 255) * 4;
    const int tid = threadIdx.x;

    for (int t = tid; t < 960; t += 256) {
        int row = t / 96, c8 = (t % 96) * 8;
        int np = n0 - 6 + row;
        float4 lo = make_float4(0.f, 0.f, 0.f, 0.f);
        float4 hi = make_float4(0.f, 0.f, 0.f, 0.f);
        if (np >= 0) {
            bf16x8 vv = *(const bf16x8*)&qkvb[((size_t)((b << 10) + np)) * 2304 + 1536 + c8];
            lo.x = b2f(vv[0]); lo.y = b2f(vv[1]); lo.z = b2f(vv[2]); lo.w = b2f(vv[3]);
            hi.x = b2f(vv[4]); hi.y = b2f(vv[5]); hi.z = b2f(vv[6]); hi.w = b2f(vv[7]);
        }
        *(float4*)&vt[row][c8] = lo;
        *(float4*)&vt[row][c8 + 4] = hi;
    }
    if (tid < 48) {
        int ni = tid / 12, h = tid % 12;
        int bn = (b << 10) + n0 + ni;
        const float* pb = &plig[(size_t)bn * 128];
        float lg[5]; float mx = -1e30f;
#pragma unroll
        for (int p = 0; p < 5; ++p) { lg[p] = pb[h * 5 + p]; mx = fmaxf(mx, lg[p]); }
        float sum = 0.f;
#pragma unroll
        for (int p = 0; p < 5; ++p) { lg[p] = __expf(lg[p] - mx); sum += lg[p]; }
        float e1 = 0.f;
#pragma unroll
        for (int p = 0; p < 5; ++p) {
            float wv = lg[p] / sum;
            wts4[ni][h * 5 + p] = wv;
            e1 += wv * logf(wv + 1e-8f);
        }
        float g = sigmoidf_(gl[(size_t)bn * 128 + h]);
        gate4[ni][h] = g;
        float e2 = g * logf(g + 1e-8f) + (1.f - g) * logf(1.f - g + 1e-8f);
        idg4[ni][h] = sigmoidf_(pb[60 + h]) * sigmoidf_(idst[h]);
        entb[tid] = e1 + e2;
    }
    float4 wl[7], wsv[3];
    if (tid < 192) {
        int c4 = tid * 4;
#pragma unroll
        for (int t = 0; t < 7; ++t) wl[t] = *(const float4*)&firlT[t * 768 + c4];
#pragma unroll
        for (int t = 0; t < 3; ++t) wsv[t] = *(const float4*)&firsT[t * 768 + c4];
    }
    __syncthreads();

#pragma unroll 1
    for (int ni = 0; ni < 4; ++ni) {
        if (tid < 192) {
            int c4 = tid * 4;
            float4 as = make_float4(0.f, 0.f, 0.f, 0.f);
            float4 al = make_float4(0.f, 0.f, 0.f, 0.f);
#pragma unroll
            for (int t = 0; t < 7; ++t) {
                float4 vv = *(const float4*)&vt[ni + t][c4];
                al.x += wl[t].x * vv.x; al.y += wl[t].y * vv.y;
                al.z += wl[t].z * vv.z; al.w += wl[t].w * vv.w;
                if (t >= 4) {
                    as.x += wsv[t - 4].x * vv.x; as.y += wsv[t - 4].y * vv.y;
                    as.z += wsv[t - 4].z * vv.z; as.w += wsv[t - 4].w * vv.w;
                }
            }
            *(float4*)&fsb[c4] = as;
            *(float4*)&flb[c4] = al;
        }
        __syncthreads();
        if (tid < 192) {
            int c4 = tid * 4;
            int h = c4 >> 6, d = c4 & 63;
            float4 ms = *(const float4*)&fsb[c4];
            float4 ml = *(const float4*)&flb[c4];
#pragma unroll
            for (int hh = 0; hh < 12; ++hh) {
                float mw = mixw[hh * 12 + h];
                float4 fsv = *(const float4*)&fsb[hh * 64 + d];
                float4 flv = *(const float4*)&flb[hh * 64 + d];
                ms.x += mw * fsv.x; ms.y += mw * fsv.y;
                ms.z += mw * fsv.z; ms.w += mw * fsv.w;
                ml.x += mw * flv.x; ml.y += mw * flv.y;
                ml.z += mw * flv.z; ml.w += mw * flv.w;
            }
            int bn = (b << 10) + n0 + ni;
            short4 ds = *(const short4*)&deltab[(size_t)bn * 768 + c4];
            short4 is = *(const short4*)&idoutb[(size_t)bn * 768 + c4];
            float4 vv = *(const float4*)&vt[ni + 6][c4];
            float ig = idg4[ni][h];
            const float* wp = &wts4[ni][h * 5];
            float4 pr;
            pr.x = ms.x * wp[0] + ml.x * wp[1] + b2f(ds.x) * wp[2] + vv.x * wp[3] + b2f(is.x) * ig * wp[4];
            pr.y = ms.y * wp[0] + ml.y * wp[1] + b2f(ds.y) * wp[2] + vv.y * wp[3] + b2f(is.y) * ig * wp[4];
            pr.z = ms.z * wp[0] + ml.z * wp[1] + b2f(ds.z) * wp[2] + vv.z * wp[3] + b2f(is.z) * ig * wp[4];
            pr.w = ms.w * wp[0] + ml.w * wp[1] + b2f(ds.w) * wp[2] + vv.w * wp[3] + b2f(is.w) * ig * wp[4];
            float g = gate4[ni][h];
            short4 o;
            o.x = bf16c(pr.x * g); o.y = bf16c(pr.y * g);
            o.z = bf16c(pr.z * g); o.w = bf16c(pr.w * g);
            *(short4*)&ctxb[(size_t)bn * 768 + c4] = o;
        }
        __syncthreads();
    }
    if (tid == 0) {
        float s = 0.f;
#pragma unroll
        for (int i = 0; i < 48; ++i) s += entb[i];
        entslots[blk] = s;
    }
}

extern "C" void kernel_launch(void* const* d_in, const int* in_sizes, int n_in,
                              void* d_out, int out_size, void* d_ws, size_t ws_size,
                              hipStream_t stream) {
    const float* x        = (const float*)d_in[0];
    const float* w_qkv    = (const float*)d_in[1];
    const float* w_proj   = (const float*)d_in[2];
    const float* b_proj   = (const float*)d_in[3];
    const float* fir_s_w  = (const float*)d_in[4];
    const float* fir_l_w  = (const float*)d_in[5];
    const float* mixw     = (const float*)d_in[6];
    const float* w_prune  = (const float*)d_in[7];
    const float* b_prune  = (const float*)d_in[8];
    const float* w_g1     = (const float*)d_in[9];
    const float* b_g1     = (const float*)d_in[10];
    const float* w_g2     = (const float*)d_in[11];
    const float* b_g2     = (const float*)d_in[12];
    const float* w_id     = (const float*)d_in[13];
    const float* id_st    = (const float*)d_in[14];
    const float* w_idgate = (const float*)d_in[15];
    const float* b_idgate = (const float*)d_in[16];
    float* out = (float*)d_out;
    float* ws  = (float*)d_ws;

    float* Ub    = ws + WS_U;
    float* plig  = ws + WS_PLIG;
    float* gl    = ws + WS_GL;
    float* ent   = ws + WS_ENT;
    float* firsT = ws + WS_FIRST;
    float* firlT = ws + WS_FIRLT;
    float* cbias = ws + WS_CBIAS;
    float* gbias = ws + WS_GBIAS;
    short* wsh   = (short*)(ws + WS_SH);
    short* xb      = wsh + SH_XB;
    short* qkvb    = wsh + SH_QKVB;
    short* idoutb  = wsh + SH_IDOUT;
    short* hdnb    = wsh + SH_HDNB;
    short* ctxb    = wsh + SH_CTXB;
    short* deltab  = wsh + SH_DELTA;
    short* Qsb16   = wsh + SH_QS;
    short* Kntb16  = wsh + SH_KNT;
    short* Wb16    = wsh + SH_W;
    short* Atb16   = wsh + SH_AT;
    short* wcat2T  = wsh + SH_WCAT2T;
    short* g2T     = wsh + SH_G2T;
    short* wprojT  = wsh + SH_WPROJT;

    // conversions + prep (z=4: small weights; z=5: x -> bf16)
    convert_w_kernel<<<dim3(12, 36, 6), 256, 0, stream>>>(w_qkv, w_id, w_g1, w_proj,
            wcat2T, wprojT, w_prune, w_idgate, b_prune, b_idgate, b_g1, b_g2,
            w_g2, fir_s_w, fir_l_w, g2T, cbias, gbias, firsT, firlT, x, xb);
    // fused main projection: qkv | idout | gelu-hdn | prune+idgate logits
    // 128x64 tiles: 62 col-tiles x 32 row-tiles = 1984 blocks
    gemm_main<<<dim3(62, 32), 256, 0, stream>>>(xb, wcat2T, cbias,
                                                qkvb, idoutb, hdnb, plig);
    // gate GEMM (blocks 0..31) + delta-rule preprocessing (32..799), one launch
    pre_gl_kernel<<<dim3(800), 256, 0, stream>>>(qkvb, Qsb16, Kntb16, Ub, Wb16, Atb16,
                                                 hdnb, g2T, gbias, gl);
    // sequential chunk scan
    scan_kernel<<<dim3(BH, 4), 256, 0, stream>>>(Qsb16, Kntb16, Ub, Wb16, Atb16, deltab);
    // FIR + mix + prune + gates + entropies (writes bf16 context directly)
    paths_kernel<<<dim3(1024), 256, 0, stream>>>(qkvb, deltab, idoutb, plig, gl,
                                                 mixw, id_st, firsT, firlT, ctxb, ent);
    // output projection (128x64 tiles: 12 x 32 = 384 blocks) + entropy finalize
    gemm_mfma<<<dim3(12, 32), 256, 0, stream>>>(ctxb, wprojT, b_proj, out, BN, 768, 768,
                                                ent, out + OUT_ELEMS);
}